// Round 5
// baseline (3832.293 us; speedup 1.0000x reference)
//
#include <hip/hip_runtime.h>
#include <hip/hip_bf16.h>
#include <stdint.h>

typedef __hip_bfloat16 bf16;
typedef unsigned short u16;
typedef unsigned int u32;
typedef __bf16 v8bf __attribute__((ext_vector_type(8)));
typedef float v4f __attribute__((ext_vector_type(4)));

// Problem constants
#define NB 16384            // B
#define MROWS 147456        // T*B*3 token rows

__device__ __forceinline__ float b2f(u16 u) {
  union { u32 u; float f; } v; v.u = ((u32)u) << 16; return v.f;
}
__device__ __forceinline__ u16 f2b(float f) {
  union { float f; u32 u; } v; v.f = f;
  u32 u = v.u;
  return (u16)((u + 0x7fffu + ((u >> 16) & 1u)) >> 16);
}

// ---------------------------------------------------------------------------
// Weight prep: read f32 weights, write transposed bf16 [N][K] (gemm_bt form);
// pack bq/bk/bv contiguously as f32. Per-layer element layout in wt:
// q 0, k 65536, v 131072 (together a 768x256 [N][K] matrix for fused QKV),
// o 196608, W1T 262144 (1024x256), W2T 524288 (256x1024); layer stride 786432.
// ---------------------------------------------------------------------------
__global__ __launch_bounds__(256)
void prep_weights(const float* Wq, const float* Wk, const float* Wv, const float* Wo,
                  const float* W1, const float* W2,
                  const float* bq, const float* bk, const float* bv,
                  bf16* wt, float* bqkv)
{
  if (blockIdx.x == 6144) {   // bias-pack block
    for (int e = threadIdx.x; e < 1536; e += 256) {
      int l = e / 768;
      int rem = e - l * 768;
      int wsel = rem >> 8;
      int col = rem & 255;
      const float* s = (wsel == 0) ? bq : (wsel == 1) ? bk : bv;
      bqkv[e] = s[l * 256 + col];
    }
    return;
  }
  int gid = blockIdx.x * 256 + threadIdx.x;   // [0, 1572864)
  int layer = (gid >= 786432) ? 1 : 0;
  int r = gid - layer * 786432;
  const float* src; int K, N, e, outoff;
  if (r < 262144) {
    int which = r >> 16;
    e = r & 65535; K = 256; N = 256;
    const float* w = (which == 0) ? Wq : (which == 1) ? Wk : (which == 2) ? Wv : Wo;
    src = w + layer * 65536;
    outoff = layer * 786432 + which * 65536;
  } else if (r < 524288) {
    e = r - 262144; K = 256; N = 1024;
    src = W1 + layer * 262144;
    outoff = layer * 786432 + 262144;
  } else {
    e = r - 524288; K = 1024; N = 256;
    src = W2 + layer * 262144;
    outoff = layer * 786432 + 524288;
  }
  int n = e / K, kk = e - n * K;
  ((u16*)wt)[outoff + e] = f2b(src[kk * N + n]);
}

// ---------------------------------------------------------------------------
// Fused graph-message build + layer-0 LN1: compute x row, write x (f32),
// LayerNorm it, write h (bf16). 1 wave per row, 4 rows per block.
// ---------------------------------------------------------------------------
__global__ __launch_bounds__(256)
void build_ln(const float* __restrict__ T, const float* __restrict__ P,
              const float* __restrict__ gp, const float* __restrict__ bp,
              float* __restrict__ X, bf16* __restrict__ H, int row0)
{
  const int lane = threadIdx.x & 63;
  const int lrow = blockIdx.x * 4 + (threadIdx.x >> 6);
  const int row = row0 + lrow;
  const int d0 = lane * 4;
  int n = row / 3;
  int t = row - n * 3;
  float4 v;
  if (t == 2) {
    v = *(const float4*)(T + (size_t)n * 256 + d0);
  } else {
    int tm = n >> 14, b = n & 16383;
    const int srcT[6] = {1, 2,  0, 2,  1, 0};
    const int srcP[6] = {0, 2,  0, 1,  1, 2};
    const float sg[6] = {-1.f, -1.f,  1.f, -1.f,  1.f, 1.f};
    int idx = tm * 2 + t;
    float4 tv = *(const float4*)(T + ((size_t)(srcT[idx] * NB + b)) * 256 + d0);
    float4 pv = *(const float4*)(P + ((size_t)(srcP[idx] * NB + b)) * 256 + d0);
    float s = sg[idx];
    v.x = tv.x + s * pv.x;
    v.y = tv.y + s * pv.y;
    v.z = tv.z + s * pv.z;
    v.w = tv.w + s * pv.w;
  }
  *(float4*)(X + (size_t)lrow * 256 + d0) = v;
  float s = v.x + v.y + v.z + v.w;
  float q = v.x * v.x + v.y * v.y + v.z * v.z + v.w * v.w;
  #pragma unroll
  for (int m = 32; m > 0; m >>= 1) {
    s += __shfl_xor(s, m, 64);
    q += __shfl_xor(q, m, 64);
  }
  float mean = s * (1.f / 256.f);
  float var = q * (1.f / 256.f) - mean * mean;
  float r = rsqrtf(var + 1e-5f);
  float4 gv = *(const float4*)(gp + d0);
  float4 bv = *(const float4*)(bp + d0);
  ushort4 outv;
  outv.x = f2b((v.x - mean) * r * gv.x + bv.x);
  outv.y = f2b((v.y - mean) * r * gv.y + bv.y);
  outv.z = f2b((v.z - mean) * r * gv.z + bv.z);
  outv.w = f2b((v.w - mean) * r * gv.w + bv.w);
  *(ushort4*)((u16*)H + (size_t)lrow * 256 + d0) = outv;
}

// ---------------------------------------------------------------------------
// LayerNorm over D=256 (f32 in, bf16 out). 1 wave per row, 4 rows per block.
// ---------------------------------------------------------------------------
__global__ __launch_bounds__(256)
void ln_rows(const float* __restrict__ xp, const float* __restrict__ gp,
             const float* __restrict__ bp, bf16* __restrict__ hp)
{
  const int lane = threadIdx.x & 63;
  const int row = blockIdx.x * 4 + (threadIdx.x >> 6);
  float4 rv = *(const float4*)(xp + (size_t)row * 256 + lane * 4);
  float v0 = rv.x, v1 = rv.y, v2 = rv.z, v3 = rv.w;
  float s = v0 + v1 + v2 + v3;
  float q = v0 * v0 + v1 * v1 + v2 * v2 + v3 * v3;
  #pragma unroll
  for (int m = 32; m > 0; m >>= 1) {
    s += __shfl_xor(s, m, 64);
    q += __shfl_xor(q, m, 64);
  }
  float mean = s * (1.f / 256.f);
  float var = q * (1.f / 256.f) - mean * mean;
  float r = rsqrtf(var + 1e-5f);
  float4 gv = *(const float4*)(gp + lane * 4);
  float4 bv = *(const float4*)(bp + lane * 4);
  ushort4 outv;
  outv.x = f2b((v0 - mean) * r * gv.x + bv.x);
  outv.y = f2b((v1 - mean) * r * gv.y + bv.y);
  outv.z = f2b((v2 - mean) * r * gv.z + bv.z);
  outv.w = f2b((v3 - mean) * r * gv.w + bv.w);
  *(ushort4*)((u16*)hp + (size_t)row * 256 + lane * 4) = outv;
}

// ---------------------------------------------------------------------------
// GEMM: C[M,N] = A[M,K] @ Bt[N,K]^T (+bias[col]) (+res f32) (+relu).
// A,Bt bf16; C bf16 or f32 (OUTF32). fp32 MFMA accumulate.
// 128x128 tile, 4 waves, 4x4 of 16x16x32 per wave, BK=32.
// K-loop: buffer_load->VGPR register prefetch (depth 3: two reg tile-sets)
// + LDS double buffer + ds_write. Plain VGPR loads are NOT drained by
// __syncthreads (unlike global_load_lds, whose vmcnt(0)-before-barrier
// exposed full load latency in rounds 3-4) -> loads stay in flight across
// barriers, ~2 K-iters of latency coverage per wave.
// ---------------------------------------------------------------------------
#define LDT(dst, t) do {                                            \
    int tt = (t) < nk ? (t) : nk - 1;                               \
    dst[0] = *(const uint4*)(pA0 + tt * 32);                        \
    dst[1] = *(const uint4*)(pA1 + tt * 32);                        \
    dst[2] = *(const uint4*)(pB0 + tt * 32);                        \
    dst[3] = *(const uint4*)(pB1 + tt * 32);                        \
  } while (0)

#define WRT(src, buf) do {                                          \
    ((uint4*)As)[(buf) * 512 + tid] = src[0];                       \
    ((uint4*)As)[(buf) * 512 + 256 + tid] = src[1];                 \
    ((uint4*)Bs)[(buf) * 512 + tid] = src[2];                       \
    ((uint4*)Bs)[(buf) * 512 + 256 + tid] = src[3];                 \
  } while (0)

#define CMPT(buf) do {                                              \
    const char* AsC = (const char*)As + (buf) * 8192;               \
    const char* BsC = (const char*)Bs + (buf) * 8192;               \
    v8bf a[4], b[4];                                                \
    _Pragma("unroll")                                               \
    for (int i = 0; i < 4; i++)                                     \
      a[i] = *(const v8bf*)(AsC + rdA + i * 1024);                  \
    _Pragma("unroll")                                               \
    for (int j = 0; j < 4; j++)                                     \
      b[j] = *(const v8bf*)(BsC + rdB + j * 1024);                  \
    _Pragma("unroll")                                               \
    for (int i = 0; i < 4; i++)                                     \
      _Pragma("unroll")                                             \
      for (int j = 0; j < 4; j++)                                   \
        acc[i][j] = __builtin_amdgcn_mfma_f32_16x16x32_bf16(        \
            a[i], b[j], acc[i][j], 0, 0, 0);                        \
  } while (0)

template<int RES, int RELU, int OUTF32>
__global__ __launch_bounds__(256)
void gemm_bt(const bf16* __restrict__ Ap, const bf16* __restrict__ Btp,
             const float* __restrict__ biasp, const float* __restrict__ resp,
             void* __restrict__ Cp, int N, int K)
{
  __shared__ __align__(16) u16 As[2 * 128 * 32];
  __shared__ __align__(16) u16 Bs[2 * 128 * 32];
  const u16* A = (const u16*)Ap;
  const u16* Bt = (const u16*)Btp;
  const int m0 = blockIdx.x * 128;
  const int n0 = blockIdx.y * 128;
  const int tid = threadIdx.x;
  const int w = tid >> 6, lane = tid & 63;
  const int waveM = (w & 1) * 64, waveN = (w >> 1) * 64;

  const int rrow = tid >> 2;          // 0..63
  const int kcol = (tid & 3) * 8;
  const u16* pA0 = A + (size_t)(m0 + rrow) * K + kcol;
  const u16* pA1 = pA0 + (size_t)64 * K;
  const u16* pB0 = Bt + (size_t)(n0 + rrow) * K + kcol;
  const u16* pB1 = pB0 + (size_t)64 * K;
  const int nk = K >> 5;

  v4f acc[4][4];
  #pragma unroll
  for (int i = 0; i < 4; i++)
    #pragma unroll
    for (int j = 0; j < 4; j++) {
      v4f zz = {0.f, 0.f, 0.f, 0.f};
      acc[i][j] = zz;
    }

  const int rdA = (waveM + (lane & 15)) * 64 + (lane >> 4) * 16;  // byte offs
  const int rdB = (waveN + (lane & 15)) * 64 + (lane >> 4) * 16;

  uint4 R[4], S[4];
  LDT(R, 0);                 // tile 0
  LDT(S, 1);                 // tile 1
  WRT(R, 0);                 // buf0 = tile 0
  LDT(R, 2);                 // tile 2 in flight
  __syncthreads();

  for (int kt = 0; kt < nk; kt += 2) {
    // even: compute buf0 (tile kt); S holds kt+1
    WRT(S, 1);
    LDT(S, kt + 3);
    CMPT(0);
    __syncthreads();
    // odd: compute buf1 (tile kt+1); R holds kt+2
    WRT(R, 0);
    LDT(R, kt + 4);
    CMPT(1);
    __syncthreads();
  }

  float bv[4];
  #pragma unroll
  for (int j = 0; j < 4; j++)
    bv[j] = biasp[n0 + waveN + j * 16 + (lane & 15)];

  #pragma unroll
  for (int i = 0; i < 4; i++) {
    #pragma unroll
    for (int r = 0; r < 4; r++) {
      int rowg = m0 + waveM + i * 16 + (lane >> 4) * 4 + r;
      size_t rb = (size_t)rowg * N;
      #pragma unroll
      for (int j = 0; j < 4; j++) {
        int colg = n0 + waveN + j * 16 + (lane & 15);
        float vv = acc[i][j][r] + bv[j];
        if (RES) vv += resp[rb + colg];
        if (RELU) vv = fmaxf(vv, 0.f);
        if (OUTF32) ((float*)Cp)[rb + colg] = vv;
        else ((u16*)Cp)[rb + colg] = f2b(vv);
      }
    }
  }
}

// ---------------------------------------------------------------------------
// Attention: seq_len 3, H=8, DH=32. Input = fused qkv buffer, row stride 768
// ([q|k|v] per row); output o, row stride 256. 8 sequences per block.
// ---------------------------------------------------------------------------
__global__ __launch_bounds__(256)
void attn(const bf16* __restrict__ qkvp, bf16* __restrict__ op)
{
  __shared__ __align__(16) u16 qs[6144], ks[6144], vs[6144];
  __shared__ float probs[8][8][9];
  const int tid = threadIdx.x;
  // 24 rows per block; qkv chunks: row*96 uint4s, [0:32)=q [32:64)=k [64:96)=v
  const uint4* g = (const uint4*)qkvp + (size_t)blockIdx.x * 24 * 96;
  for (int c = tid; c < 768; c += 256) {
    int r = c >> 5, e = c & 31;
    ((uint4*)qs)[c] = g[r * 96 + e];
    ((uint4*)ks)[c] = g[r * 96 + 32 + e];
    ((uint4*)vs)[c] = g[r * 96 + 64 + e];
  }
  __syncthreads();
  if (tid < 64) {
    int s = tid >> 3, h = tid & 7;
    int base = s * 768 + h * 32;
    float sc[3][3];
    #pragma unroll
    for (int i = 0; i < 3; i++)
      #pragma unroll
      for (int j = 0; j < 3; j++) {
        float sum = 0.f;
        #pragma unroll
        for (int d = 0; d < 32; d++)
          sum += b2f(qs[base + i * 256 + d]) * b2f(ks[base + j * 256 + d]);
        sc[i][j] = sum * 0.17677669529663687f;   // DH^-0.5
      }
    #pragma unroll
    for (int i = 0; i < 3; i++) {
      float m = fmaxf(sc[i][0], fmaxf(sc[i][1], sc[i][2]));
      float e0 = __expf(sc[i][0] - m);
      float e1 = __expf(sc[i][1] - m);
      float e2 = __expf(sc[i][2] - m);
      float inv = 1.f / (e0 + e1 + e2);
      probs[s][h][i * 3 + 0] = e0 * inv;
      probs[s][h][i * 3 + 1] = e1 * inv;
      probs[s][h][i * 3 + 2] = e2 * inv;
    }
  }
  __syncthreads();
  u16* og = (u16*)op + (size_t)blockIdx.x * 6144;
  for (int c = tid; c < 6144; c += 256) {
    int lrow = c >> 8, hd = c & 255;
    int s = lrow / 3, i = lrow - s * 3;
    int h = hd >> 5;
    float p0 = probs[s][h][i * 3 + 0];
    float p1 = probs[s][h][i * 3 + 1];
    float p2 = probs[s][h][i * 3 + 2];
    float o = p0 * b2f(vs[s * 768 + hd])
            + p1 * b2f(vs[s * 768 + 256 + hd])
            + p2 * b2f(vs[s * 768 + 512 + hd]);
    og[c] = f2b(o);
  }
}

// ---------------------------------------------------------------------------
// Final LN + mean over 3 tokens (f32 in, f32 out). 1 wave/seq, 4 seq/block.
// ---------------------------------------------------------------------------
__global__ __launch_bounds__(256)
void ln_final_mean(const float* __restrict__ xp, const float* __restrict__ gp,
                   const float* __restrict__ bp, float* __restrict__ outp)
{
  const int lane = threadIdx.x & 63;
  const int n = blockIdx.x * 4 + (threadIdx.x >> 6);
  float4 gv = *(const float4*)(gp + lane * 4);
  float4 bv4 = *(const float4*)(bp + lane * 4);
  float a0 = 0.f, a1 = 0.f, a2 = 0.f, a3 = 0.f;
  for (int t = 0; t < 3; t++) {
    float4 rv = *(const float4*)(xp + ((size_t)n * 3 + t) * 256 + lane * 4);
    float v0 = rv.x, v1 = rv.y, v2 = rv.z, v3 = rv.w;
    float s = v0 + v1 + v2 + v3;
    float q = v0 * v0 + v1 * v1 + v2 * v2 + v3 * v3;
    #pragma unroll
    for (int m = 32; m > 0; m >>= 1) {
      s += __shfl_xor(s, m, 64);
      q += __shfl_xor(q, m, 64);
    }
    float mean = s * (1.f / 256.f);
    float var = q * (1.f / 256.f) - mean * mean;
    float r = rsqrtf(var + 1e-5f);
    a0 += (v0 - mean) * r * gv.x + bv4.x;
    a1 += (v1 - mean) * r * gv.y + bv4.y;
    a2 += (v2 - mean) * r * gv.z + bv4.z;
    a3 += (v3 - mean) * r * gv.w + bv4.w;
  }
  const float third = 1.f / 3.f;
  float4 outv;
  outv.x = a0 * third;
  outv.y = a1 * third;
  outv.z = a2 * third;
  outv.w = a3 * third;
  *(float4*)(outp + (size_t)n * 256 + lane * 4) = outv;
}

// ---------------------------------------------------------------------------
extern "C" void kernel_launch(void* const* d_in, const int* in_sizes, int n_in,
                              void* d_out, int out_size, void* d_ws, size_t ws_size,
                              hipStream_t stream)
{
  const float* term = (const float*)d_in[0];
  const float* pred = (const float*)d_in[1];
  const float* Wq  = (const float*)d_in[2];
  const float* Wk  = (const float*)d_in[3];
  const float* Wv  = (const float*)d_in[4];
  const float* Wo  = (const float*)d_in[5];
  const float* bq  = (const float*)d_in[6];
  const float* bk  = (const float*)d_in[7];
  const float* bvv = (const float*)d_in[8];
  const float* bo  = (const float*)d_in[9];
  const float* ln1g = (const float*)d_in[10];
  const float* ln1b = (const float*)d_in[11];
  const float* ln2g = (const float*)d_in[12];
  const float* ln2b = (const float*)d_in[13];
  const float* W1  = (const float*)d_in[14];
  const float* b1  = (const float*)d_in[15];
  const float* W2  = (const float*)d_in[16];
  const float* b2  = (const float*)d_in[17];
  const float* lnfg = (const float*)d_in[18];
  const float* lnfb = (const float*)d_in[19];

  // --- choose chunk count from ws_size (deterministic; same every call).
  // Per chunk per row: x f32 (1024B) + h bf16 (512B) + qkv bf16 (1536B) +
  // o bf16 (512B) = 3584B; FFN hidden f (2048B) aliases qkv+o.
  int nch = 128;
  for (int c = 1; c <= 128; c *= 2) {
    size_t Mc = (size_t)MROWS / c;
    size_t need = 4ull * 1024 * 1024 + Mc * 3584ull;
    if (need <= ws_size) { nch = c; break; }
  }
  const size_t Mc = (size_t)MROWS / nch;     // multiple of 1152
  const int mBlocks = (int)(Mc / 128);

  char* ws = (char*)d_ws;
  bf16* wt   = (bf16*)ws;                    // 1572864 el (3 MB)
  float* bqkv = (float*)(ws + 3145728);      // 1536 f32
  float* x = (float*)(ws + 4194304);         // Mc*256 f32
  bf16* h = (bf16*)(x + Mc * 256);           // Mc*256 bf16
  bf16* qkv = h + Mc * 256;                  // Mc*768 bf16
  bf16* o = qkv + Mc * 768;                  // Mc*256 bf16
  bf16* f = qkv;                             // FFN hidden aliases qkv+o

  prep_weights<<<6145, 256, 0, stream>>>(Wq, Wk, Wv, Wo, W1, W2, bq, bk, bvv, wt, bqkv);

  for (int ch = 0; ch < nch; ch++) {
    const int row0 = (int)(ch * Mc);
    // fused: build x rows + layer-0 LN1 -> h
    build_ln<<<(int)(Mc / 4), 256, 0, stream>>>(term, pred, ln1g, ln1b, x, h, row0);
    for (int l = 0; l < 2; l++) {
      const bf16* wl = wt + l * 786432;
      if (l > 0)
        ln_rows<<<(int)(Mc / 4), 256, 0, stream>>>(x, ln1g + l * 256, ln1b + l * 256, h);
      // fused QKV: one GEMM, N=768 ([WqT;WkT;WvT] is 768x256 in wt)
      gemm_bt<0, 0, 0><<<dim3(mBlocks, 6), 256, 0, stream>>>(
          h, wl, bqkv + l * 768, nullptr, qkv, 768, 256);
      attn<<<(int)(Mc / 24), 256, 0, stream>>>(qkv, o);
      gemm_bt<1, 0, 1><<<dim3(mBlocks, 2), 256, 0, stream>>>(
          o, wl + 196608, bo + l * 256, x, x, 256, 256);
      ln_rows<<<(int)(Mc / 4), 256, 0, stream>>>(x, ln2g + l * 256, ln2b + l * 256, h);
      gemm_bt<0, 1, 0><<<dim3(mBlocks, 8), 256, 0, stream>>>(
          h, wl + 262144, b1 + l * 1024, nullptr, f, 1024, 256);
      gemm_bt<1, 0, 1><<<dim3(mBlocks, 2), 256, 0, stream>>>(
          f, wl + 524288, b2 + l * 256, x, x, 256, 1024);
    }
    ln_final_mean<<<(int)(Mc / 12), 256, 0, stream>>>(
        x, lnfg, lnfb, (float*)d_out + (size_t)(row0 / 3) * 256);
  }
}

// Round 6
// 2421.452 us; speedup vs baseline: 1.5826x; 1.5826x over previous
//
#include <hip/hip_runtime.h>
#include <hip/hip_bf16.h>
#include <stdint.h>

typedef __hip_bfloat16 bf16;
typedef unsigned short u16;
typedef unsigned int u32;
typedef __bf16 v8bf __attribute__((ext_vector_type(8)));
typedef float v4f __attribute__((ext_vector_type(4)));

// Problem constants
#define NB 16384            // B
#define MROWS 147456        // T*B*3 token rows

__device__ __forceinline__ float b2f(u16 u) {
  union { u32 u; float f; } v; v.u = ((u32)u) << 16; return v.f;
}
__device__ __forceinline__ u16 f2b(float f) {
  union { float f; u32 u; } v; v.f = f;
  u32 u = v.u;
  return (u16)((u + 0x7fffu + ((u >> 16) & 1u)) >> 16);
}

// ---------------------------------------------------------------------------
// Weight prep: read f32 weights, write transposed bf16 [N][K] (gemm_bt form);
// pack bq/bk/bv contiguously as f32. Per-layer element layout in wt:
// q 0, k 65536, v 131072 (together a 768x256 [N][K] matrix for fused QKV),
// o 196608, W1T 262144 (1024x256), W2T 524288 (256x1024); layer stride 786432.
// ---------------------------------------------------------------------------
__global__ __launch_bounds__(256)
void prep_weights(const float* Wq, const float* Wk, const float* Wv, const float* Wo,
                  const float* W1, const float* W2,
                  const float* bq, const float* bk, const float* bv,
                  bf16* wt, float* bqkv)
{
  if (blockIdx.x == 6144) {   // bias-pack block
    for (int e = threadIdx.x; e < 1536; e += 256) {
      int l = e / 768;
      int rem = e - l * 768;
      int wsel = rem >> 8;
      int col = rem & 255;
      const float* s = (wsel == 0) ? bq : (wsel == 1) ? bk : bv;
      bqkv[e] = s[l * 256 + col];
    }
    return;
  }
  int gid = blockIdx.x * 256 + threadIdx.x;   // [0, 1572864)
  int layer = (gid >= 786432) ? 1 : 0;
  int r = gid - layer * 786432;
  const float* src; int K, N, e, outoff;
  if (r < 262144) {
    int which = r >> 16;
    e = r & 65535; K = 256; N = 256;
    const float* w = (which == 0) ? Wq : (which == 1) ? Wk : (which == 2) ? Wv : Wo;
    src = w + layer * 65536;
    outoff = layer * 786432 + which * 65536;
  } else if (r < 524288) {
    e = r - 262144; K = 256; N = 1024;
    src = W1 + layer * 262144;
    outoff = layer * 786432 + 262144;
  } else {
    e = r - 524288; K = 1024; N = 256;
    src = W2 + layer * 262144;
    outoff = layer * 786432 + 524288;
  }
  int n = e / K, kk = e - n * K;
  ((u16*)wt)[outoff + e] = f2b(src[kk * N + n]);
}

// ---------------------------------------------------------------------------
// Fused graph-message build + layer-0 LN1: compute x row, write x (f32),
// LayerNorm it, write h (bf16). 1 wave per row, 4 rows per block.
// ---------------------------------------------------------------------------
__global__ __launch_bounds__(256)
void build_ln(const float* __restrict__ T, const float* __restrict__ P,
              const float* __restrict__ gp, const float* __restrict__ bp,
              float* __restrict__ X, bf16* __restrict__ H, int row0)
{
  const int lane = threadIdx.x & 63;
  const int lrow = blockIdx.x * 4 + (threadIdx.x >> 6);
  const int row = row0 + lrow;
  const int d0 = lane * 4;
  int n = row / 3;
  int t = row - n * 3;
  float4 v;
  if (t == 2) {
    v = *(const float4*)(T + (size_t)n * 256 + d0);
  } else {
    int tm = n >> 14, b = n & 16383;
    const int srcT[6] = {1, 2,  0, 2,  1, 0};
    const int srcP[6] = {0, 2,  0, 1,  1, 2};
    const float sg[6] = {-1.f, -1.f,  1.f, -1.f,  1.f, 1.f};
    int idx = tm * 2 + t;
    float4 tv = *(const float4*)(T + ((size_t)(srcT[idx] * NB + b)) * 256 + d0);
    float4 pv = *(const float4*)(P + ((size_t)(srcP[idx] * NB + b)) * 256 + d0);
    float s = sg[idx];
    v.x = tv.x + s * pv.x;
    v.y = tv.y + s * pv.y;
    v.z = tv.z + s * pv.z;
    v.w = tv.w + s * pv.w;
  }
  *(float4*)(X + (size_t)lrow * 256 + d0) = v;
  float s = v.x + v.y + v.z + v.w;
  float q = v.x * v.x + v.y * v.y + v.z * v.z + v.w * v.w;
  #pragma unroll
  for (int m = 32; m > 0; m >>= 1) {
    s += __shfl_xor(s, m, 64);
    q += __shfl_xor(q, m, 64);
  }
  float mean = s * (1.f / 256.f);
  float var = q * (1.f / 256.f) - mean * mean;
  float r = rsqrtf(var + 1e-5f);
  float4 gv = *(const float4*)(gp + d0);
  float4 bv = *(const float4*)(bp + d0);
  ushort4 outv;
  outv.x = f2b((v.x - mean) * r * gv.x + bv.x);
  outv.y = f2b((v.y - mean) * r * gv.y + bv.y);
  outv.z = f2b((v.z - mean) * r * gv.z + bv.z);
  outv.w = f2b((v.w - mean) * r * gv.w + bv.w);
  *(ushort4*)((u16*)H + (size_t)lrow * 256 + d0) = outv;
}

// ---------------------------------------------------------------------------
// LayerNorm over D=256 (f32 in, bf16 out). 1 wave per row, 4 rows per block.
// ---------------------------------------------------------------------------
__global__ __launch_bounds__(256)
void ln_rows(const float* __restrict__ xp, const float* __restrict__ gp,
             const float* __restrict__ bp, bf16* __restrict__ hp)
{
  const int lane = threadIdx.x & 63;
  const int row = blockIdx.x * 4 + (threadIdx.x >> 6);
  float4 rv = *(const float4*)(xp + (size_t)row * 256 + lane * 4);
  float v0 = rv.x, v1 = rv.y, v2 = rv.z, v3 = rv.w;
  float s = v0 + v1 + v2 + v3;
  float q = v0 * v0 + v1 * v1 + v2 * v2 + v3 * v3;
  #pragma unroll
  for (int m = 32; m > 0; m >>= 1) {
    s += __shfl_xor(s, m, 64);
    q += __shfl_xor(q, m, 64);
  }
  float mean = s * (1.f / 256.f);
  float var = q * (1.f / 256.f) - mean * mean;
  float r = rsqrtf(var + 1e-5f);
  float4 gv = *(const float4*)(gp + lane * 4);
  float4 bv = *(const float4*)(bp + lane * 4);
  ushort4 outv;
  outv.x = f2b((v0 - mean) * r * gv.x + bv.x);
  outv.y = f2b((v1 - mean) * r * gv.y + bv.y);
  outv.z = f2b((v2 - mean) * r * gv.z + bv.z);
  outv.w = f2b((v3 - mean) * r * gv.w + bv.w);
  *(ushort4*)((u16*)hp + (size_t)row * 256 + lane * 4) = outv;
}

// ---------------------------------------------------------------------------
// LDS-FREE GEMM: C[M,N] = A[M,K] @ Bt[N,K]^T (+bias) (+res f32) (+relu).
// Each wave owns an independent 64x64 tile (4x4 of 16x16x32 MFMA); A and B
// fragments are loaded straight from global with dwordx4 (the MFMA operand
// layout -- lane: row=lane&15, k=(lane>>4)*8 -- is 16 contiguous bytes of a
// row-major [.][K] matrix). NO LDS, NO barriers: avoids the vmcnt(0)
// barrier-drain (r3/r4, ~100us plateau) and the register-prefetch spill
// (r5, 552MB scratch). N,K are compile-time so the K-loop fully unrolls and
// the compiler software-pipelines the loads with staggered vmcnt.
// ---------------------------------------------------------------------------
template<int N, int K, int RES, int RELU, int OUTF32>
__global__ __launch_bounds__(256)
void gemm_bt(const bf16* __restrict__ Ap, const bf16* __restrict__ Btp,
             const float* __restrict__ biasp, const float* __restrict__ resp,
             void* __restrict__ Cp)
{
  const u16* A = (const u16*)Ap;
  const u16* Bt = (const u16*)Btp;
  const int tid = threadIdx.x;
  const int w = tid >> 6, lane = tid & 63;
  const int m0 = blockIdx.x * 128 + (w & 1) * 64;   // wave row base
  const int n0 = blockIdx.y * 128 + (w >> 1) * 64;  // wave col base
  const int fr = lane & 15;          // fragment row/col within 16
  const int kq = (lane >> 4) * 8;    // k sub-offset within 32

  const u16* pA = A + (size_t)(m0 + fr) * K + kq;
  const u16* pB = Bt + (size_t)(n0 + fr) * K + kq;

  v4f acc[4][4];
  #pragma unroll
  for (int i = 0; i < 4; i++)
    #pragma unroll
    for (int j = 0; j < 4; j++) {
      v4f zz = {0.f, 0.f, 0.f, 0.f};
      acc[i][j] = zz;
    }

  #pragma unroll 2
  for (int kb = 0; kb < K; kb += 32) {
    v8bf a[4], b[4];
    #pragma unroll
    for (int i = 0; i < 4; i++)
      a[i] = *(const v8bf*)(pA + (size_t)i * 16 * K + kb);
    #pragma unroll
    for (int j = 0; j < 4; j++)
      b[j] = *(const v8bf*)(pB + (size_t)j * 16 * K + kb);
    #pragma unroll
    for (int i = 0; i < 4; i++)
      #pragma unroll
      for (int j = 0; j < 4; j++)
        acc[i][j] = __builtin_amdgcn_mfma_f32_16x16x32_bf16(a[i], b[j], acc[i][j], 0, 0, 0);
  }

  float bv[4];
  #pragma unroll
  for (int j = 0; j < 4; j++)
    bv[j] = biasp[n0 + j * 16 + (lane & 15)];

  #pragma unroll
  for (int i = 0; i < 4; i++) {
    #pragma unroll
    for (int r = 0; r < 4; r++) {
      int rowg = m0 + i * 16 + (lane >> 4) * 4 + r;
      size_t rb = (size_t)rowg * N;
      #pragma unroll
      for (int j = 0; j < 4; j++) {
        int colg = n0 + j * 16 + (lane & 15);
        float vv = acc[i][j][r] + bv[j];
        if (RES) vv += resp[rb + colg];
        if (RELU) vv = fmaxf(vv, 0.f);
        if (OUTF32) ((float*)Cp)[rb + colg] = vv;
        else ((u16*)Cp)[rb + colg] = f2b(vv);
      }
    }
  }
}

// ---------------------------------------------------------------------------
// Attention: seq_len 3, H=8, DH=32. Input = fused qkv buffer, row stride 768
// ([q|k|v] per row); output o, row stride 256. 8 sequences per block.
// ---------------------------------------------------------------------------
__global__ __launch_bounds__(256)
void attn(const bf16* __restrict__ qkvp, bf16* __restrict__ op)
{
  __shared__ __align__(16) u16 qs[6144], ks[6144], vs[6144];
  __shared__ float probs[8][8][9];
  const int tid = threadIdx.x;
  // 24 rows per block; qkv chunks: row*96 uint4s, [0:32)=q [32:64)=k [64:96)=v
  const uint4* g = (const uint4*)qkvp + (size_t)blockIdx.x * 24 * 96;
  for (int c = tid; c < 768; c += 256) {
    int r = c >> 5, e = c & 31;
    ((uint4*)qs)[c] = g[r * 96 + e];
    ((uint4*)ks)[c] = g[r * 96 + 32 + e];
    ((uint4*)vs)[c] = g[r * 96 + 64 + e];
  }
  __syncthreads();
  if (tid < 64) {
    int s = tid >> 3, h = tid & 7;
    int base = s * 768 + h * 32;
    float sc[3][3];
    #pragma unroll
    for (int i = 0; i < 3; i++)
      #pragma unroll
      for (int j = 0; j < 3; j++) {
        float sum = 0.f;
        #pragma unroll
        for (int d = 0; d < 32; d++)
          sum += b2f(qs[base + i * 256 + d]) * b2f(ks[base + j * 256 + d]);
        sc[i][j] = sum * 0.17677669529663687f;   // DH^-0.5
      }
    #pragma unroll
    for (int i = 0; i < 3; i++) {
      float m = fmaxf(sc[i][0], fmaxf(sc[i][1], sc[i][2]));
      float e0 = __expf(sc[i][0] - m);
      float e1 = __expf(sc[i][1] - m);
      float e2 = __expf(sc[i][2] - m);
      float inv = 1.f / (e0 + e1 + e2);
      probs[s][h][i * 3 + 0] = e0 * inv;
      probs[s][h][i * 3 + 1] = e1 * inv;
      probs[s][h][i * 3 + 2] = e2 * inv;
    }
  }
  __syncthreads();
  u16* og = (u16*)op + (size_t)blockIdx.x * 6144;
  for (int c = tid; c < 6144; c += 256) {
    int lrow = c >> 8, hd = c & 255;
    int s = lrow / 3, i = lrow - s * 3;
    int h = hd >> 5;
    float p0 = probs[s][h][i * 3 + 0];
    float p1 = probs[s][h][i * 3 + 1];
    float p2 = probs[s][h][i * 3 + 2];
    float o = p0 * b2f(vs[s * 768 + hd])
            + p1 * b2f(vs[s * 768 + 256 + hd])
            + p2 * b2f(vs[s * 768 + 512 + hd]);
    og[c] = f2b(o);
  }
}

// ---------------------------------------------------------------------------
// Final LN + mean over 3 tokens (f32 in, f32 out). 1 wave/seq, 4 seq/block.
// ---------------------------------------------------------------------------
__global__ __launch_bounds__(256)
void ln_final_mean(const float* __restrict__ xp, const float* __restrict__ gp,
                   const float* __restrict__ bp, float* __restrict__ outp)
{
  const int lane = threadIdx.x & 63;
  const int n = blockIdx.x * 4 + (threadIdx.x >> 6);
  float4 gv = *(const float4*)(gp + lane * 4);
  float4 bv4 = *(const float4*)(bp + lane * 4);
  float a0 = 0.f, a1 = 0.f, a2 = 0.f, a3 = 0.f;
  for (int t = 0; t < 3; t++) {
    float4 rv = *(const float4*)(xp + ((size_t)n * 3 + t) * 256 + lane * 4);
    float v0 = rv.x, v1 = rv.y, v2 = rv.z, v3 = rv.w;
    float s = v0 + v1 + v2 + v3;
    float q = v0 * v0 + v1 * v1 + v2 * v2 + v3 * v3;
    #pragma unroll
    for (int m = 32; m > 0; m >>= 1) {
      s += __shfl_xor(s, m, 64);
      q += __shfl_xor(q, m, 64);
    }
    float mean = s * (1.f / 256.f);
    float var = q * (1.f / 256.f) - mean * mean;
    float r = rsqrtf(var + 1e-5f);
    a0 += (v0 - mean) * r * gv.x + bv4.x;
    a1 += (v1 - mean) * r * gv.y + bv4.y;
    a2 += (v2 - mean) * r * gv.z + bv4.z;
    a3 += (v3 - mean) * r * gv.w + bv4.w;
  }
  const float third = 1.f / 3.f;
  float4 outv;
  outv.x = a0 * third;
  outv.y = a1 * third;
  outv.z = a2 * third;
  outv.w = a3 * third;
  *(float4*)(outp + (size_t)n * 256 + lane * 4) = outv;
}

// ---------------------------------------------------------------------------
extern "C" void kernel_launch(void* const* d_in, const int* in_sizes, int n_in,
                              void* d_out, int out_size, void* d_ws, size_t ws_size,
                              hipStream_t stream)
{
  const float* term = (const float*)d_in[0];
  const float* pred = (const float*)d_in[1];
  const float* Wq  = (const float*)d_in[2];
  const float* Wk  = (const float*)d_in[3];
  const float* Wv  = (const float*)d_in[4];
  const float* Wo  = (const float*)d_in[5];
  const float* bq  = (const float*)d_in[6];
  const float* bk  = (const float*)d_in[7];
  const float* bvv = (const float*)d_in[8];
  const float* bo  = (const float*)d_in[9];
  const float* ln1g = (const float*)d_in[10];
  const float* ln1b = (const float*)d_in[11];
  const float* ln2g = (const float*)d_in[12];
  const float* ln2b = (const float*)d_in[13];
  const float* W1  = (const float*)d_in[14];
  const float* b1  = (const float*)d_in[15];
  const float* W2  = (const float*)d_in[16];
  const float* b2  = (const float*)d_in[17];
  const float* lnfg = (const float*)d_in[18];
  const float* lnfb = (const float*)d_in[19];

  // --- choose chunk count from ws_size (deterministic; same every call).
  // Per chunk per row: x f32 (1024B) + h bf16 (512B) + qkv bf16 (1536B) +
  // o bf16 (512B) = 3584B; FFN hidden f (2048B) aliases qkv+o.
  int nch = 128;
  for (int c = 1; c <= 128; c *= 2) {
    size_t Mc = (size_t)MROWS / c;
    size_t need = 4ull * 1024 * 1024 + Mc * 3584ull;
    if (need <= ws_size) { nch = c; break; }
  }
  const size_t Mc = (size_t)MROWS / nch;     // multiple of 1152
  const int mBlocks = (int)(Mc / 128);

  char* ws = (char*)d_ws;
  bf16* wt   = (bf16*)ws;                    // 1572864 el (3 MB)
  float* bqkv = (float*)(ws + 3145728);      // 1536 f32
  float* x = (float*)(ws + 4194304);         // Mc*256 f32
  bf16* h = (bf16*)(x + Mc * 256);           // Mc*256 bf16
  bf16* qkv = h + Mc * 256;                  // Mc*768 bf16
  bf16* o = qkv + Mc * 768;                  // Mc*256 bf16
  bf16* f = qkv;                             // FFN hidden aliases qkv+o

  prep_weights<<<6145, 256, 0, stream>>>(Wq, Wk, Wv, Wo, W1, W2, bq, bk, bvv, wt, bqkv);

  for (int ch = 0; ch < nch; ch++) {
    const int row0 = (int)(ch * Mc);
    // fused: build x rows + layer-0 LN1 -> h
    build_ln<<<(int)(Mc / 4), 256, 0, stream>>>(term, pred, ln1g, ln1b, x, h, row0);
    for (int l = 0; l < 2; l++) {
      const bf16* wl = wt + l * 786432;
      if (l > 0)
        ln_rows<<<(int)(Mc / 4), 256, 0, stream>>>(x, ln1g + l * 256, ln1b + l * 256, h);
      // fused QKV: one GEMM, N=768 ([WqT;WkT;WvT] is 768x256 in wt)
      gemm_bt<768, 256, 0, 0, 0><<<dim3(mBlocks, 6), 256, 0, stream>>>(
          h, wl, bqkv + l * 768, nullptr, qkv);
      attn<<<(int)(Mc / 24), 256, 0, stream>>>(qkv, o);
      gemm_bt<256, 256, 1, 0, 1><<<dim3(mBlocks, 2), 256, 0, stream>>>(
          o, wl + 196608, bo + l * 256, x, x);
      ln_rows<<<(int)(Mc / 4), 256, 0, stream>>>(x, ln2g + l * 256, ln2b + l * 256, h);
      gemm_bt<1024, 256, 0, 1, 0><<<dim3(mBlocks, 8), 256, 0, stream>>>(
          h, wl + 262144, b1 + l * 1024, nullptr, f);
      gemm_bt<256, 1024, 1, 0, 1><<<dim3(mBlocks, 2), 256, 0, stream>>>(
          f, wl + 524288, b2 + l * 256, x, x);
    }
    ln_final_mean<<<(int)(Mc / 12), 256, 0, stream>>>(
        x, lnfg, lnfb, (float*)d_out + (size_t)(row0 / 3) * 256);
  }
}

// Round 7
// 2023.614 us; speedup vs baseline: 1.8938x; 1.1966x over previous
//
#include <hip/hip_runtime.h>
#include <hip/hip_bf16.h>
#include <stdint.h>

typedef __hip_bfloat16 bf16;
typedef unsigned short u16;
typedef unsigned int u32;
typedef __bf16 v8bf __attribute__((ext_vector_type(8)));
typedef float v4f __attribute__((ext_vector_type(4)));

// Problem constants
#define NB 16384            // B
#define MROWS 147456        // T*B*3 token rows

__device__ __forceinline__ float b2f(u16 u) {
  union { u32 u; float f; } v; v.u = ((u32)u) << 16; return v.f;
}
__device__ __forceinline__ u16 f2b(float f) {
  union { float f; u32 u; } v; v.f = f;
  u32 u = v.u;
  return (u16)((u + 0x7fffu + ((u >> 16) & 1u)) >> 16);
}
__device__ __forceinline__ void async16(const u16* g, u16* lds) {
  __builtin_amdgcn_global_load_lds((const __attribute__((address_space(1))) void*)g,
                                   (__attribute__((address_space(3))) void*)lds,
                                   16, 0, 0);
}

// ---------------------------------------------------------------------------
// Weight prep: read f32 weights, write transposed bf16 [N][K] (gemm_bt form);
// pack bq/bk/bv contiguously as f32. Per-layer element layout in wt:
// q 0, k 65536, v 131072 (together a 768x256 [N][K] matrix for fused QKV),
// o 196608, W1T 262144 (1024x256), W2T 524288 (256x1024); layer stride 786432.
// ---------------------------------------------------------------------------
__global__ __launch_bounds__(256)
void prep_weights(const float* Wq, const float* Wk, const float* Wv, const float* Wo,
                  const float* W1, const float* W2,
                  const float* bq, const float* bk, const float* bv,
                  bf16* wt, float* bqkv)
{
  if (blockIdx.x == 6144) {   // bias-pack block
    for (int e = threadIdx.x; e < 1536; e += 256) {
      int l = e / 768;
      int rem = e - l * 768;
      int wsel = rem >> 8;
      int col = rem & 255;
      const float* s = (wsel == 0) ? bq : (wsel == 1) ? bk : bv;
      bqkv[e] = s[l * 256 + col];
    }
    return;
  }
  int gid = blockIdx.x * 256 + threadIdx.x;   // [0, 1572864)
  int layer = (gid >= 786432) ? 1 : 0;
  int r = gid - layer * 786432;
  const float* src; int K, N, e, outoff;
  if (r < 262144) {
    int which = r >> 16;
    e = r & 65535; K = 256; N = 256;
    const float* w = (which == 0) ? Wq : (which == 1) ? Wk : (which == 2) ? Wv : Wo;
    src = w + layer * 65536;
    outoff = layer * 786432 + which * 65536;
  } else if (r < 524288) {
    e = r - 262144; K = 256; N = 1024;
    src = W1 + layer * 262144;
    outoff = layer * 786432 + 262144;
  } else {
    e = r - 524288; K = 1024; N = 256;
    src = W2 + layer * 262144;
    outoff = layer * 786432 + 524288;
  }
  int n = e / K, kk = e - n * K;
  ((u16*)wt)[outoff + e] = f2b(src[kk * N + n]);
}

// ---------------------------------------------------------------------------
// Fused graph-message build + layer-0 LN1 -> x (f32) and h (bf16).
// ---------------------------------------------------------------------------
__global__ __launch_bounds__(256)
void build_ln(const float* __restrict__ T, const float* __restrict__ P,
              const float* __restrict__ gp, const float* __restrict__ bp,
              float* __restrict__ X, bf16* __restrict__ H, int row0)
{
  const int lane = threadIdx.x & 63;
  const int lrow = blockIdx.x * 4 + (threadIdx.x >> 6);
  const int row = row0 + lrow;
  const int d0 = lane * 4;
  int n = row / 3;
  int t = row - n * 3;
  float4 v;
  if (t == 2) {
    v = *(const float4*)(T + (size_t)n * 256 + d0);
  } else {
    int tm = n >> 14, b = n & 16383;
    const int srcT[6] = {1, 2,  0, 2,  1, 0};
    const int srcP[6] = {0, 2,  0, 1,  1, 2};
    const float sg[6] = {-1.f, -1.f,  1.f, -1.f,  1.f, 1.f};
    int idx = tm * 2 + t;
    float4 tv = *(const float4*)(T + ((size_t)(srcT[idx] * NB + b)) * 256 + d0);
    float4 pv = *(const float4*)(P + ((size_t)(srcP[idx] * NB + b)) * 256 + d0);
    float s = sg[idx];
    v.x = tv.x + s * pv.x;
    v.y = tv.y + s * pv.y;
    v.z = tv.z + s * pv.z;
    v.w = tv.w + s * pv.w;
  }
  *(float4*)(X + (size_t)lrow * 256 + d0) = v;
  float s = v.x + v.y + v.z + v.w;
  float q = v.x * v.x + v.y * v.y + v.z * v.z + v.w * v.w;
  #pragma unroll
  for (int m = 32; m > 0; m >>= 1) {
    s += __shfl_xor(s, m, 64);
    q += __shfl_xor(q, m, 64);
  }
  float mean = s * (1.f / 256.f);
  float var = q * (1.f / 256.f) - mean * mean;
  float r = rsqrtf(var + 1e-5f);
  float4 gv = *(const float4*)(gp + d0);
  float4 bv = *(const float4*)(bp + d0);
  ushort4 outv;
  outv.x = f2b((v.x - mean) * r * gv.x + bv.x);
  outv.y = f2b((v.y - mean) * r * gv.y + bv.y);
  outv.z = f2b((v.z - mean) * r * gv.z + bv.z);
  outv.w = f2b((v.w - mean) * r * gv.w + bv.w);
  *(ushort4*)((u16*)H + (size_t)lrow * 256 + d0) = outv;
}

// ---------------------------------------------------------------------------
// LayerNorm over D=256 (f32 in, bf16 out). 1 wave per row, 4 rows per block.
// ---------------------------------------------------------------------------
__global__ __launch_bounds__(256)
void ln_rows(const float* __restrict__ xp, const float* __restrict__ gp,
             const float* __restrict__ bp, bf16* __restrict__ hp)
{
  const int lane = threadIdx.x & 63;
  const int row = blockIdx.x * 4 + (threadIdx.x >> 6);
  float4 rv = *(const float4*)(xp + (size_t)row * 256 + lane * 4);
  float v0 = rv.x, v1 = rv.y, v2 = rv.z, v3 = rv.w;
  float s = v0 + v1 + v2 + v3;
  float q = v0 * v0 + v1 * v1 + v2 * v2 + v3 * v3;
  #pragma unroll
  for (int m = 32; m > 0; m >>= 1) {
    s += __shfl_xor(s, m, 64);
    q += __shfl_xor(q, m, 64);
  }
  float mean = s * (1.f / 256.f);
  float var = q * (1.f / 256.f) - mean * mean;
  float r = rsqrtf(var + 1e-5f);
  float4 gv = *(const float4*)(gp + lane * 4);
  float4 bv = *(const float4*)(bp + lane * 4);
  ushort4 outv;
  outv.x = f2b((v0 - mean) * r * gv.x + bv.x);
  outv.y = f2b((v1 - mean) * r * gv.y + bv.y);
  outv.z = f2b((v2 - mean) * r * gv.z + bv.z);
  outv.w = f2b((v3 - mean) * r * gv.w + bv.w);
  *(ushort4*)((u16*)hp + (size_t)row * 256 + lane * 4) = outv;
}

// ---------------------------------------------------------------------------
// GEMM (r4 structure, best measured): C = A @ Bt^T (+bias) (+res f32).
// 128x128 tile, dbuf global_load_lds staging, one barrier per BK=32 iter.
// ---------------------------------------------------------------------------
template<int RES, int OUTF32>
__global__ __launch_bounds__(256)
void gemm_bt(const bf16* __restrict__ Ap, const bf16* __restrict__ Btp,
             const float* __restrict__ biasp, const float* __restrict__ resp,
             void* __restrict__ Cp, int N, int K)
{
  __shared__ __align__(16) u16 As[2 * 128 * 32];
  __shared__ __align__(16) u16 Bs[2 * 128 * 32];
  const u16* A = (const u16*)Ap;
  const u16* Bt = (const u16*)Btp;
  const int m0 = blockIdx.x * 128;
  const int n0 = blockIdx.y * 128;
  const int tid = threadIdx.x;
  const int w = tid >> 6, lane = tid & 63;
  const int waveM = (w & 1) * 64, waveN = (w >> 1) * 64;

  const int rrow = tid >> 2;
  const int kcol = (tid & 3) * 8;
  const u16* pA0 = A + (size_t)(m0 + rrow) * K + kcol;
  const u16* pA1 = pA0 + (size_t)64 * K;
  const u16* pB0 = Bt + (size_t)(n0 + rrow) * K + kcol;
  const u16* pB1 = pB0 + (size_t)64 * K;

  v4f acc[4][4];
  #pragma unroll
  for (int i = 0; i < 4; i++)
    #pragma unroll
    for (int j = 0; j < 4; j++) {
      v4f zz = {0.f, 0.f, 0.f, 0.f};
      acc[i][j] = zz;
    }

  const int rdA = (waveM + (lane & 15)) * 64 + (lane >> 4) * 16;
  const int rdB = (waveN + (lane & 15)) * 64 + (lane >> 4) * 16;
  const int nk = K >> 5;

  async16(pA0, As + w * 512);        async16(pA1, As + 2048 + w * 512);
  async16(pB0, Bs + w * 512);        async16(pB1, Bs + 2048 + w * 512);
  pA0 += 32; pA1 += 32; pB0 += 32; pB1 += 32;

  int cur = 0;
  for (int kt = 0; kt < nk; kt++) {
    __syncthreads();
    if (kt + 1 < nk) {
      const int nxt = (cur ^ 1) * 4096;
      async16(pA0, As + nxt + w * 512);        async16(pA1, As + nxt + 2048 + w * 512);
      async16(pB0, Bs + nxt + w * 512);        async16(pB1, Bs + nxt + 2048 + w * 512);
      pA0 += 32; pA1 += 32; pB0 += 32; pB1 += 32;
    }
    const char* AsC = (const char*)(As + cur * 4096);
    const char* BsC = (const char*)(Bs + cur * 4096);
    v8bf a[4], b[4];
    #pragma unroll
    for (int i = 0; i < 4; i++)
      a[i] = *(const v8bf*)(AsC + rdA + i * 1024);
    #pragma unroll
    for (int j = 0; j < 4; j++)
      b[j] = *(const v8bf*)(BsC + rdB + j * 1024);
    #pragma unroll
    for (int i = 0; i < 4; i++)
      #pragma unroll
      for (int j = 0; j < 4; j++)
        acc[i][j] = __builtin_amdgcn_mfma_f32_16x16x32_bf16(a[i], b[j], acc[i][j], 0, 0, 0);
    cur ^= 1;
  }

  float bv[4];
  #pragma unroll
  for (int j = 0; j < 4; j++)
    bv[j] = biasp[n0 + waveN + j * 16 + (lane & 15)];

  #pragma unroll
  for (int i = 0; i < 4; i++) {
    #pragma unroll
    for (int r = 0; r < 4; r++) {
      int rowg = m0 + waveM + i * 16 + (lane >> 4) * 4 + r;
      size_t rb = (size_t)rowg * N;
      #pragma unroll
      for (int j = 0; j < 4; j++) {
        int colg = n0 + waveN + j * 16 + (lane & 15);
        float vv = acc[i][j][r] + bv[j];
        if (RES) vv += resp[rb + colg];
        if (OUTF32) ((float*)Cp)[rb + colg] = vv;
        else ((u16*)Cp)[rb + colg] = f2b(vv);
      }
    }
  }
}

// ---------------------------------------------------------------------------
// FUSED FFN: x += relu(LN2(x) @ W1 + b1) @ W2 + b2 for a 32-row slab.
// h-slab (16 KB) and f-slab (64 KB) live entirely in LDS (80 KB -> 2 blk/CU);
// W1T/W2T stream from L2 (hot across all blocks). HBM traffic per slab:
// read x 32 KB + write x 32 KB -- eliminates the f 604 MB/layer round-trip
// that made FFN1/FFN2 the slowest dispatches in r3-r6.
// LDS tiles: [32 rows][32 k] bf16 (2 KB, 64 B row stride = m97's proven
// conflict-free fragment layout); tile t covers k in [32t, 32t+32).
// ---------------------------------------------------------------------------
__global__ __launch_bounds__(256)
void ffn_fused(float* __restrict__ xp,
               const bf16* __restrict__ W1Tp, const bf16* __restrict__ W2Tp,
               const float* __restrict__ gp, const float* __restrict__ bp,
               const float* __restrict__ b1p, const float* __restrict__ b2p)
{
  __shared__ __align__(16) u16 hs[8 * 1024];     // 8 tiles  (K=256)
  __shared__ __align__(16) u16 fs[32 * 1024];    // 32 tiles (FF=1024)
  const int tid = threadIdx.x;
  const int w = tid >> 6, lane = tid & 63;
  const int ln15 = lane & 15, lq = lane >> 4;
  const int r0 = blockIdx.x * 32;
  const u16* W1T = (const u16*)W1Tp;
  const u16* W2T = (const u16*)W2Tp;

  // ---- stage 1: LN2 of 32 rows -> hs
  #pragma unroll
  for (int rr = 0; rr < 8; rr++) {
    int row = rr * 4 + w;
    int d0 = lane * 4;
    float4 v = *(const float4*)(xp + (size_t)(r0 + row) * 256 + d0);
    float s = v.x + v.y + v.z + v.w;
    float q = v.x * v.x + v.y * v.y + v.z * v.z + v.w * v.w;
    #pragma unroll
    for (int m = 32; m > 0; m >>= 1) {
      s += __shfl_xor(s, m, 64);
      q += __shfl_xor(q, m, 64);
    }
    float mean = s * (1.f / 256.f);
    float var = q * (1.f / 256.f) - mean * mean;
    float r = rsqrtf(var + 1e-5f);
    float4 gv = *(const float4*)(gp + d0);
    float4 bv = *(const float4*)(bp + d0);
    ushort4 o4;
    o4.x = f2b((v.x - mean) * r * gv.x + bv.x);
    o4.y = f2b((v.y - mean) * r * gv.y + bv.y);
    o4.z = f2b((v.z - mean) * r * gv.z + bv.z);
    o4.w = f2b((v.w - mean) * r * gv.w + bv.w);
    *(ushort4*)(hs + (d0 >> 5) * 1024 + row * 32 + (d0 & 31)) = o4;
  }
  __syncthreads();

  // ---- stage 2: FFN1. Wave w covers FF cols [w*256, w*256+256) in 4 passes
  // of 32 rows x 64 cols. acc -> +b1 -> relu -> fs (A-frag tiled layout).
  #pragma unroll 1
  for (int p = 0; p < 4; p++) {
    const int nb = w * 256 + p * 64;
    v4f acc[2][4];
    #pragma unroll
    for (int i = 0; i < 2; i++)
      #pragma unroll
      for (int j = 0; j < 4; j++) {
        v4f zz = {0.f, 0.f, 0.f, 0.f};
        acc[i][j] = zz;
      }
    #pragma unroll
    for (int kk = 0; kk < 8; kk++) {
      v8bf a[2], b[4];
      #pragma unroll
      for (int i = 0; i < 2; i++)
        a[i] = *(const v8bf*)(hs + kk * 1024 + (ln15 + 16 * i) * 32 + lq * 8);
      #pragma unroll
      for (int j = 0; j < 4; j++)
        b[j] = *(const v8bf*)(W1T + (size_t)(nb + 16 * j + ln15) * 256 + kk * 32 + lq * 8);
      #pragma unroll
      for (int i = 0; i < 2; i++)
        #pragma unroll
        for (int j = 0; j < 4; j++)
          acc[i][j] = __builtin_amdgcn_mfma_f32_16x16x32_bf16(a[i], b[j], acc[i][j], 0, 0, 0);
    }
    #pragma unroll
    for (int j = 0; j < 4; j++) {
      int col = nb + 16 * j + ln15;
      float bb = b1p[col];
      int tbase = (col >> 5) * 1024 + (col & 31);
      #pragma unroll
      for (int i = 0; i < 2; i++)
        #pragma unroll
        for (int r = 0; r < 4; r++) {
          int row = 16 * i + lq * 4 + r;
          fs[tbase + row * 32] = f2b(fmaxf(acc[i][j][r] + bb, 0.f));
        }
    }
  }
  __syncthreads();

  // ---- stage 3: FFN2. Wave w covers out cols [w*64, w*64+64), K=1024.
  const int cb = w * 64;
  v4f acc2[2][4];
  #pragma unroll
  for (int i = 0; i < 2; i++)
    #pragma unroll
    for (int j = 0; j < 4; j++) {
      v4f zz = {0.f, 0.f, 0.f, 0.f};
      acc2[i][j] = zz;
    }
  #pragma unroll 4
  for (int kk = 0; kk < 32; kk++) {
    v8bf a[2], b[4];
    #pragma unroll
    for (int i = 0; i < 2; i++)
      a[i] = *(const v8bf*)(fs + kk * 1024 + (ln15 + 16 * i) * 32 + lq * 8);
    #pragma unroll
    for (int j = 0; j < 4; j++)
      b[j] = *(const v8bf*)(W2T + (size_t)(cb + 16 * j + ln15) * 1024 + kk * 32 + lq * 8);
    #pragma unroll
    for (int i = 0; i < 2; i++)
      #pragma unroll
      for (int j = 0; j < 4; j++)
        acc2[i][j] = __builtin_amdgcn_mfma_f32_16x16x32_bf16(a[i], b[j], acc2[i][j], 0, 0, 0);
  }
  // ---- epilogue: x += acc2 + b2 (each (row,col) touched by exactly 1 lane)
  #pragma unroll
  for (int j = 0; j < 4; j++) {
    int colg = cb + 16 * j + ln15;
    float bb = b2p[colg];
    #pragma unroll
    for (int i = 0; i < 2; i++)
      #pragma unroll
      for (int r = 0; r < 4; r++) {
        int rowg = r0 + 16 * i + lq * 4 + r;
        size_t idx = (size_t)rowg * 256 + colg;
        xp[idx] += acc2[i][j][r] + bb;
      }
  }
}

// ---------------------------------------------------------------------------
// Attention: seq_len 3, H=8, DH=32. Input = fused qkv buffer, row stride 768
// ([q|k|v] per row); output o, row stride 256. 8 sequences per block.
// ---------------------------------------------------------------------------
__global__ __launch_bounds__(256)
void attn(const bf16* __restrict__ qkvp, bf16* __restrict__ op)
{
  __shared__ __align__(16) u16 qs[6144], ks[6144], vs[6144];
  __shared__ float probs[8][8][9];
  const int tid = threadIdx.x;
  const uint4* g = (const uint4*)qkvp + (size_t)blockIdx.x * 24 * 96;
  for (int c = tid; c < 768; c += 256) {
    int r = c >> 5, e = c & 31;
    ((uint4*)qs)[c] = g[r * 96 + e];
    ((uint4*)ks)[c] = g[r * 96 + 32 + e];
    ((uint4*)vs)[c] = g[r * 96 + 64 + e];
  }
  __syncthreads();
  if (tid < 64) {
    int s = tid >> 3, h = tid & 7;
    int base = s * 768 + h * 32;
    float sc[3][3];
    #pragma unroll
    for (int i = 0; i < 3; i++)
      #pragma unroll
      for (int j = 0; j < 3; j++) {
        float sum = 0.f;
        #pragma unroll
        for (int d = 0; d < 32; d++)
          sum += b2f(qs[base + i * 256 + d]) * b2f(ks[base + j * 256 + d]);
        sc[i][j] = sum * 0.17677669529663687f;
      }
    #pragma unroll
    for (int i = 0; i < 3; i++) {
      float m = fmaxf(sc[i][0], fmaxf(sc[i][1], sc[i][2]));
      float e0 = __expf(sc[i][0] - m);
      float e1 = __expf(sc[i][1] - m);
      float e2 = __expf(sc[i][2] - m);
      float inv = 1.f / (e0 + e1 + e2);
      probs[s][h][i * 3 + 0] = e0 * inv;
      probs[s][h][i * 3 + 1] = e1 * inv;
      probs[s][h][i * 3 + 2] = e2 * inv;
    }
  }
  __syncthreads();
  u16* og = (u16*)op + (size_t)blockIdx.x * 6144;
  for (int c = tid; c < 6144; c += 256) {
    int lrow = c >> 8, hd = c & 255;
    int s = lrow / 3, i = lrow - s * 3;
    int h = hd >> 5;
    float p0 = probs[s][h][i * 3 + 0];
    float p1 = probs[s][h][i * 3 + 1];
    float p2 = probs[s][h][i * 3 + 2];
    float o = p0 * b2f(vs[s * 768 + hd])
            + p1 * b2f(vs[s * 768 + 256 + hd])
            + p2 * b2f(vs[s * 768 + 512 + hd]);
    og[c] = f2b(o);
  }
}

// ---------------------------------------------------------------------------
// Final LN + mean over 3 tokens (f32 in, f32 out). 1 wave/seq, 4 seq/block.
// ---------------------------------------------------------------------------
__global__ __launch_bounds__(256)
void ln_final_mean(const float* __restrict__ xp, const float* __restrict__ gp,
                   const float* __restrict__ bp, float* __restrict__ outp)
{
  const int lane = threadIdx.x & 63;
  const int n = blockIdx.x * 4 + (threadIdx.x >> 6);
  float4 gv = *(const float4*)(gp + lane * 4);
  float4 bv4 = *(const float4*)(bp + lane * 4);
  float a0 = 0.f, a1 = 0.f, a2 = 0.f, a3 = 0.f;
  for (int t = 0; t < 3; t++) {
    float4 rv = *(const float4*)(xp + ((size_t)n * 3 + t) * 256 + lane * 4);
    float v0 = rv.x, v1 = rv.y, v2 = rv.z, v3 = rv.w;
    float s = v0 + v1 + v2 + v3;
    float q = v0 * v0 + v1 * v1 + v2 * v2 + v3 * v3;
    #pragma unroll
    for (int m = 32; m > 0; m >>= 1) {
      s += __shfl_xor(s, m, 64);
      q += __shfl_xor(q, m, 64);
    }
    float mean = s * (1.f / 256.f);
    float var = q * (1.f / 256.f) - mean * mean;
    float r = rsqrtf(var + 1e-5f);
    a0 += (v0 - mean) * r * gv.x + bv4.x;
    a1 += (v1 - mean) * r * gv.y + bv4.y;
    a2 += (v2 - mean) * r * gv.z + bv4.z;
    a3 += (v3 - mean) * r * gv.w + bv4.w;
  }
  const float third = 1.f / 3.f;
  float4 outv;
  outv.x = a0 * third;
  outv.y = a1 * third;
  outv.z = a2 * third;
  outv.w = a3 * third;
  *(float4*)(outp + (size_t)n * 256 + lane * 4) = outv;
}

// ---------------------------------------------------------------------------
extern "C" void kernel_launch(void* const* d_in, const int* in_sizes, int n_in,
                              void* d_out, int out_size, void* d_ws, size_t ws_size,
                              hipStream_t stream)
{
  const float* term = (const float*)d_in[0];
  const float* pred = (const float*)d_in[1];
  const float* Wq  = (const float*)d_in[2];
  const float* Wk  = (const float*)d_in[3];
  const float* Wv  = (const float*)d_in[4];
  const float* Wo  = (const float*)d_in[5];
  const float* bq  = (const float*)d_in[6];
  const float* bk  = (const float*)d_in[7];
  const float* bvv = (const float*)d_in[8];
  const float* bo  = (const float*)d_in[9];
  const float* ln1g = (const float*)d_in[10];
  const float* ln1b = (const float*)d_in[11];
  const float* ln2g = (const float*)d_in[12];
  const float* ln2b = (const float*)d_in[13];
  const float* W1  = (const float*)d_in[14];
  const float* b1  = (const float*)d_in[15];
  const float* W2  = (const float*)d_in[16];
  const float* b2  = (const float*)d_in[17];
  const float* lnfg = (const float*)d_in[18];
  const float* lnfb = (const float*)d_in[19];

  // Per chunk per row: x f32 (1024B) + h bf16 (512B) + qkv bf16 (1536B) +
  // o bf16 (512B) = 3584B. (FFN hidden now lives in LDS.)
  int nch = 128;
  for (int c = 1; c <= 128; c *= 2) {
    size_t Mc = (size_t)MROWS / c;
    size_t need = 4ull * 1024 * 1024 + Mc * 3584ull;
    if (need <= ws_size) { nch = c; break; }
  }
  const size_t Mc = (size_t)MROWS / nch;     // multiple of 1152
  const int mBlocks = (int)(Mc / 128);

  char* ws = (char*)d_ws;
  bf16* wt   = (bf16*)ws;                    // 1572864 el (3 MB)
  float* bqkv = (float*)(ws + 3145728);      // 1536 f32
  float* x = (float*)(ws + 4194304);         // Mc*256 f32
  bf16* h = (bf16*)(x + Mc * 256);           // Mc*256 bf16
  bf16* qkv = h + Mc * 256;                  // Mc*768 bf16
  bf16* o = qkv + Mc * 768;                  // Mc*256 bf16

  prep_weights<<<6145, 256, 0, stream>>>(Wq, Wk, Wv, Wo, W1, W2, bq, bk, bvv, wt, bqkv);

  for (int ch = 0; ch < nch; ch++) {
    const int row0 = (int)(ch * Mc);
    build_ln<<<(int)(Mc / 4), 256, 0, stream>>>(term, pred, ln1g, ln1b, x, h, row0);
    for (int l = 0; l < 2; l++) {
      const bf16* wl = wt + l * 786432;
      if (l > 0)
        ln_rows<<<(int)(Mc / 4), 256, 0, stream>>>(x, ln1g + l * 256, ln1b + l * 256, h);
      gemm_bt<0, 0><<<dim3(mBlocks, 6), 256, 0, stream>>>(
          h, wl, bqkv + l * 768, nullptr, qkv, 768, 256);
      attn<<<(int)(Mc / 24), 256, 0, stream>>>(qkv, o);
      gemm_bt<1, 1><<<dim3(mBlocks, 2), 256, 0, stream>>>(
          o, wl + 196608, bo + l * 256, x, x, 256, 256);
      ffn_fused<<<(int)(Mc / 32), 256, 0, stream>>>(
          x, (const bf16*)(wl + 262144), (const bf16*)(wl + 524288),
          ln2g + l * 256, ln2b + l * 256, b1 + l * 1024, b2 + l * 256);
    }
    ln_final_mean<<<(int)(Mc / 12), 256, 0, stream>>>(
        x, lnfg, lnfb, (float*)d_out + (size_t)(row0 / 3) * 256);
  }
}

// Round 8
// 1941.681 us; speedup vs baseline: 1.9737x; 1.0422x over previous
//
#include <hip/hip_runtime.h>
#include <hip/hip_bf16.h>
#include <stdint.h>

typedef __hip_bfloat16 bf16;
typedef unsigned short u16;
typedef unsigned int u32;
typedef __bf16 v8bf __attribute__((ext_vector_type(8)));
typedef float v4f __attribute__((ext_vector_type(4)));

// Problem constants
#define NB 16384            // B
#define MROWS 147456        // T*B*3 token rows

__device__ __forceinline__ float b2f(u16 u) {
  union { u32 u; float f; } v; v.u = ((u32)u) << 16; return v.f;
}
__device__ __forceinline__ u16 f2b(float f) {
  union { float f; u32 u; } v; v.f = f;
  u32 u = v.u;
  return (u16)((u + 0x7fffu + ((u >> 16) & 1u)) >> 16);
}
__device__ __forceinline__ void async16(const u16* g, u16* lds) {
  __builtin_amdgcn_global_load_lds((const __attribute__((address_space(1))) void*)g,
                                   (__attribute__((address_space(3))) void*)lds,
                                   16, 0, 0);
}

// ---------------------------------------------------------------------------
// Weight prep: read f32 weights, write transposed bf16 [N][K] (gemm_bt form);
// pack bq/bk/bv contiguously as f32. Per-layer element layout in wt:
// q 0, k 65536, v 131072 (together a 768x256 [N][K] matrix for fused QKV),
// o 196608, W1T 262144 (1024x256), W2T 524288 (256x1024); layer stride 786432.
// ---------------------------------------------------------------------------
__global__ __launch_bounds__(256)
void prep_weights(const float* Wq, const float* Wk, const float* Wv, const float* Wo,
                  const float* W1, const float* W2,
                  const float* bq, const float* bk, const float* bv,
                  bf16* wt, float* bqkv)
{
  if (blockIdx.x == 6144) {   // bias-pack block
    for (int e = threadIdx.x; e < 1536; e += 256) {
      int l = e / 768;
      int rem = e - l * 768;
      int wsel = rem >> 8;
      int col = rem & 255;
      const float* s = (wsel == 0) ? bq : (wsel == 1) ? bk : bv;
      bqkv[e] = s[l * 256 + col];
    }
    return;
  }
  int gid = blockIdx.x * 256 + threadIdx.x;   // [0, 1572864)
  int layer = (gid >= 786432) ? 1 : 0;
  int r = gid - layer * 786432;
  const float* src; int K, N, e, outoff;
  if (r < 262144) {
    int which = r >> 16;
    e = r & 65535; K = 256; N = 256;
    const float* w = (which == 0) ? Wq : (which == 1) ? Wk : (which == 2) ? Wv : Wo;
    src = w + layer * 65536;
    outoff = layer * 786432 + which * 65536;
  } else if (r < 524288) {
    e = r - 262144; K = 256; N = 1024;
    src = W1 + layer * 262144;
    outoff = layer * 786432 + 262144;
  } else {
    e = r - 524288; K = 1024; N = 256;
    src = W2 + layer * 262144;
    outoff = layer * 786432 + 524288;
  }
  int n = e / K, kk = e - n * K;
  ((u16*)wt)[outoff + e] = f2b(src[kk * N + n]);
}

// ---------------------------------------------------------------------------
// Fused graph-message build + layer-0 LN1 -> x (f32) and h (bf16).
// ---------------------------------------------------------------------------
__global__ __launch_bounds__(256)
void build_ln(const float* __restrict__ T, const float* __restrict__ P,
              const float* __restrict__ gp, const float* __restrict__ bp,
              float* __restrict__ X, bf16* __restrict__ H, int row0)
{
  const int lane = threadIdx.x & 63;
  const int lrow = blockIdx.x * 4 + (threadIdx.x >> 6);
  const int row = row0 + lrow;
  const int d0 = lane * 4;
  int n = row / 3;
  int t = row - n * 3;
  float4 v;
  if (t == 2) {
    v = *(const float4*)(T + (size_t)n * 256 + d0);
  } else {
    int tm = n >> 14, b = n & 16383;
    const int srcT[6] = {1, 2,  0, 2,  1, 0};
    const int srcP[6] = {0, 2,  0, 1,  1, 2};
    const float sg[6] = {-1.f, -1.f,  1.f, -1.f,  1.f, 1.f};
    int idx = tm * 2 + t;
    float4 tv = *(const float4*)(T + ((size_t)(srcT[idx] * NB + b)) * 256 + d0);
    float4 pv = *(const float4*)(P + ((size_t)(srcP[idx] * NB + b)) * 256 + d0);
    float s = sg[idx];
    v.x = tv.x + s * pv.x;
    v.y = tv.y + s * pv.y;
    v.z = tv.z + s * pv.z;
    v.w = tv.w + s * pv.w;
  }
  *(float4*)(X + (size_t)lrow * 256 + d0) = v;
  float s = v.x + v.y + v.z + v.w;
  float q = v.x * v.x + v.y * v.y + v.z * v.z + v.w * v.w;
  #pragma unroll
  for (int m = 32; m > 0; m >>= 1) {
    s += __shfl_xor(s, m, 64);
    q += __shfl_xor(q, m, 64);
  }
  float mean = s * (1.f / 256.f);
  float var = q * (1.f / 256.f) - mean * mean;
  float r = rsqrtf(var + 1e-5f);
  float4 gv = *(const float4*)(gp + d0);
  float4 bv = *(const float4*)(bp + d0);
  ushort4 outv;
  outv.x = f2b((v.x - mean) * r * gv.x + bv.x);
  outv.y = f2b((v.y - mean) * r * gv.y + bv.y);
  outv.z = f2b((v.z - mean) * r * gv.z + bv.z);
  outv.w = f2b((v.w - mean) * r * gv.w + bv.w);
  *(ushort4*)((u16*)H + (size_t)lrow * 256 + d0) = outv;
}

// ---------------------------------------------------------------------------
// LayerNorm over D=256 (f32 in, bf16 out). 1 wave per row, 4 rows per block.
// ---------------------------------------------------------------------------
__global__ __launch_bounds__(256)
void ln_rows(const float* __restrict__ xp, const float* __restrict__ gp,
             const float* __restrict__ bp, bf16* __restrict__ hp)
{
  const int lane = threadIdx.x & 63;
  const int row = blockIdx.x * 4 + (threadIdx.x >> 6);
  float4 rv = *(const float4*)(xp + (size_t)row * 256 + lane * 4);
  float v0 = rv.x, v1 = rv.y, v2 = rv.z, v3 = rv.w;
  float s = v0 + v1 + v2 + v3;
  float q = v0 * v0 + v1 * v1 + v2 * v2 + v3 * v3;
  #pragma unroll
  for (int m = 32; m > 0; m >>= 1) {
    s += __shfl_xor(s, m, 64);
    q += __shfl_xor(q, m, 64);
  }
  float mean = s * (1.f / 256.f);
  float var = q * (1.f / 256.f) - mean * mean;
  float r = rsqrtf(var + 1e-5f);
  float4 gv = *(const float4*)(gp + lane * 4);
  float4 bv = *(const float4*)(bp + lane * 4);
  ushort4 outv;
  outv.x = f2b((v0 - mean) * r * gv.x + bv.x);
  outv.y = f2b((v1 - mean) * r * gv.y + bv.y);
  outv.z = f2b((v2 - mean) * r * gv.z + bv.z);
  outv.w = f2b((v3 - mean) * r * gv.w + bv.w);
  *(ushort4*)((u16*)hp + (size_t)row * 256 + lane * 4) = outv;
}

// ---------------------------------------------------------------------------
// GEMM (r4 structure, best measured): C = A @ Bt^T (+bias) (+res f32).
// 128x128 tile, dbuf global_load_lds staging, one barrier per BK=32 iter.
// ---------------------------------------------------------------------------
template<int RES, int OUTF32>
__global__ __launch_bounds__(256)
void gemm_bt(const bf16* __restrict__ Ap, const bf16* __restrict__ Btp,
             const float* __restrict__ biasp, const float* __restrict__ resp,
             void* __restrict__ Cp, int N, int K)
{
  __shared__ __align__(16) u16 As[2 * 128 * 32];
  __shared__ __align__(16) u16 Bs[2 * 128 * 32];
  const u16* A = (const u16*)Ap;
  const u16* Bt = (const u16*)Btp;
  const int m0 = blockIdx.x * 128;
  const int n0 = blockIdx.y * 128;
  const int tid = threadIdx.x;
  const int w = tid >> 6, lane = tid & 63;
  const int waveM = (w & 1) * 64, waveN = (w >> 1) * 64;

  const int rrow = tid >> 2;
  const int kcol = (tid & 3) * 8;
  const u16* pA0 = A + (size_t)(m0 + rrow) * K + kcol;
  const u16* pA1 = pA0 + (size_t)64 * K;
  const u16* pB0 = Bt + (size_t)(n0 + rrow) * K + kcol;
  const u16* pB1 = pB0 + (size_t)64 * K;

  v4f acc[4][4];
  #pragma unroll
  for (int i = 0; i < 4; i++)
    #pragma unroll
    for (int j = 0; j < 4; j++) {
      v4f zz = {0.f, 0.f, 0.f, 0.f};
      acc[i][j] = zz;
    }

  const int rdA = (waveM + (lane & 15)) * 64 + (lane >> 4) * 16;
  const int rdB = (waveN + (lane & 15)) * 64 + (lane >> 4) * 16;
  const int nk = K >> 5;

  async16(pA0, As + w * 512);        async16(pA1, As + 2048 + w * 512);
  async16(pB0, Bs + w * 512);        async16(pB1, Bs + 2048 + w * 512);
  pA0 += 32; pA1 += 32; pB0 += 32; pB1 += 32;

  int cur = 0;
  for (int kt = 0; kt < nk; kt++) {
    __syncthreads();
    if (kt + 1 < nk) {
      const int nxt = (cur ^ 1) * 4096;
      async16(pA0, As + nxt + w * 512);        async16(pA1, As + nxt + 2048 + w * 512);
      async16(pB0, Bs + nxt + w * 512);        async16(pB1, Bs + nxt + 2048 + w * 512);
      pA0 += 32; pA1 += 32; pB0 += 32; pB1 += 32;
    }
    const char* AsC = (const char*)(As + cur * 4096);
    const char* BsC = (const char*)(Bs + cur * 4096);
    v8bf a[4], b[4];
    #pragma unroll
    for (int i = 0; i < 4; i++)
      a[i] = *(const v8bf*)(AsC + rdA + i * 1024);
    #pragma unroll
    for (int j = 0; j < 4; j++)
      b[j] = *(const v8bf*)(BsC + rdB + j * 1024);
    #pragma unroll
    for (int i = 0; i < 4; i++)
      #pragma unroll
      for (int j = 0; j < 4; j++)
        acc[i][j] = __builtin_amdgcn_mfma_f32_16x16x32_bf16(a[i], b[j], acc[i][j], 0, 0, 0);
    cur ^= 1;
  }

  float bv[4];
  #pragma unroll
  for (int j = 0; j < 4; j++)
    bv[j] = biasp[n0 + waveN + j * 16 + (lane & 15)];

  #pragma unroll
  for (int i = 0; i < 4; i++) {
    #pragma unroll
    for (int r = 0; r < 4; r++) {
      int rowg = m0 + waveM + i * 16 + (lane >> 4) * 4 + r;
      size_t rb = (size_t)rowg * N;
      #pragma unroll
      for (int j = 0; j < 4; j++) {
        int colg = n0 + waveN + j * 16 + (lane & 15);
        float vv = acc[i][j][r] + bv[j];
        if (RES) vv += resp[rb + colg];
        if (OUTF32) ((float*)Cp)[rb + colg] = vv;
        else ((u16*)Cp)[rb + colg] = f2b(vv);
      }
    }
  }
}

// ---------------------------------------------------------------------------
// FUSED FFN v2: x += relu(LN2(x) @ W1 + b1) @ W2 + b2 for a 32-row slab.
// vs r7 (332us, MfmaUtil 9%): (a) FF processed in 2 halves of 512 so the
// f-slab is 32 KB -> total LDS 48 KB -> 3 blocks/CU (12 waves, was 2/8);
// (b) W1T/W2T B-fragments use manual 1-deep per-wave register prefetch
// (load kk+1 while MFMAing kk) -- barrier-free liveness, no r5-style spill,
// hides the ~300cyc L2 latency that dominated r7's kk loops.
// ---------------------------------------------------------------------------
__global__ __launch_bounds__(256)
void ffn_fused(float* __restrict__ xp,
               const bf16* __restrict__ W1Tp, const bf16* __restrict__ W2Tp,
               const float* __restrict__ gp, const float* __restrict__ bp,
               const float* __restrict__ b1p, const float* __restrict__ b2p)
{
  __shared__ __align__(16) u16 hs[8 * 1024];     // 16 KB  (K=256)
  __shared__ __align__(16) u16 fs[16 * 1024];    // 32 KB  (FF half = 512)
  const int tid = threadIdx.x;
  const int w = tid >> 6, lane = tid & 63;
  const int ln15 = lane & 15, lq = lane >> 4;
  const int r0 = blockIdx.x * 32;
  const u16* W1T = (const u16*)W1Tp;
  const u16* W2T = (const u16*)W2Tp;

  // ---- stage 1: LN2 of 32 rows -> hs
  #pragma unroll
  for (int rr = 0; rr < 8; rr++) {
    int row = rr * 4 + w;
    int d0 = lane * 4;
    float4 v = *(const float4*)(xp + (size_t)(r0 + row) * 256 + d0);
    float s = v.x + v.y + v.z + v.w;
    float q = v.x * v.x + v.y * v.y + v.z * v.z + v.w * v.w;
    #pragma unroll
    for (int m = 32; m > 0; m >>= 1) {
      s += __shfl_xor(s, m, 64);
      q += __shfl_xor(q, m, 64);
    }
    float mean = s * (1.f / 256.f);
    float var = q * (1.f / 256.f) - mean * mean;
    float r = rsqrtf(var + 1e-5f);
    float4 gv = *(const float4*)(gp + d0);
    float4 bv = *(const float4*)(bp + d0);
    ushort4 o4;
    o4.x = f2b((v.x - mean) * r * gv.x + bv.x);
    o4.y = f2b((v.y - mean) * r * gv.y + bv.y);
    o4.z = f2b((v.z - mean) * r * gv.z + bv.z);
    o4.w = f2b((v.w - mean) * r * gv.w + bv.w);
    *(ushort4*)(hs + (d0 >> 5) * 1024 + row * 32 + (d0 & 31)) = o4;
  }
  __syncthreads();

  const int cb = w * 64;          // out-col base for stage 3 (wave-owned)
  v4f acc2[2][4];
  #pragma unroll
  for (int i = 0; i < 2; i++)
    #pragma unroll
    for (int j = 0; j < 4; j++) {
      v4f zz = {0.f, 0.f, 0.f, 0.f};
      acc2[i][j] = zz;
    }

  for (int half = 0; half < 2; half++) {
    // ---- stage 2: f cols [half*512 .. half*512+512); wave covers 128 cols
    #pragma unroll 1
    for (int p = 0; p < 2; p++) {
      const int nb = w * 128 + p * 64;           // col within half
      const int colg0 = half * 512 + nb;         // global FF col base
      v4f acc[2][4];
      #pragma unroll
      for (int i = 0; i < 2; i++)
        #pragma unroll
        for (int j = 0; j < 4; j++) {
          v4f zz = {0.f, 0.f, 0.f, 0.f};
          acc[i][j] = zz;
        }
      const u16* bw = W1T + (size_t)(colg0 + ln15) * 256 + lq * 8;
      v8bf bcur[4];
      #pragma unroll
      for (int j = 0; j < 4; j++)
        bcur[j] = *(const v8bf*)(bw + (size_t)j * 16 * 256);
      #pragma unroll
      for (int kk = 0; kk < 8; kk++) {
        v8bf bnxt[4];
        if (kk < 7) {
          #pragma unroll
          for (int j = 0; j < 4; j++)
            bnxt[j] = *(const v8bf*)(bw + (size_t)j * 16 * 256 + (kk + 1) * 32);
        }
        v8bf a[2];
        #pragma unroll
        for (int i = 0; i < 2; i++)
          a[i] = *(const v8bf*)(hs + kk * 1024 + (ln15 + 16 * i) * 32 + lq * 8);
        #pragma unroll
        for (int i = 0; i < 2; i++)
          #pragma unroll
          for (int j = 0; j < 4; j++)
            acc[i][j] = __builtin_amdgcn_mfma_f32_16x16x32_bf16(a[i], bcur[j], acc[i][j], 0, 0, 0);
        #pragma unroll
        for (int j = 0; j < 4; j++) bcur[j] = bnxt[j];
      }
      #pragma unroll
      for (int j = 0; j < 4; j++) {
        int coll = nb + 16 * j + ln15;           // col within half
        float bb = b1p[half * 512 + coll];
        int tbase = (coll >> 5) * 1024 + (coll & 31);
        #pragma unroll
        for (int i = 0; i < 2; i++)
          #pragma unroll
          for (int r = 0; r < 4; r++) {
            int row = 16 * i + lq * 4 + r;
            fs[tbase + row * 32] = f2b(fmaxf(acc[i][j][r] + bb, 0.f));
          }
      }
    }
    __syncthreads();

    // ---- stage 3: acc2 += f_half @ W2T[cb.., k in half*512..+512)
    const u16* bw2 = W2T + (size_t)(cb + ln15) * 1024 + half * 512 + lq * 8;
    v8bf ccur[4];
    #pragma unroll
    for (int j = 0; j < 4; j++)
      ccur[j] = *(const v8bf*)(bw2 + (size_t)j * 16 * 1024);
    #pragma unroll
    for (int kk = 0; kk < 16; kk++) {
      v8bf cnxt[4];
      if (kk < 15) {
        #pragma unroll
        for (int j = 0; j < 4; j++)
          cnxt[j] = *(const v8bf*)(bw2 + (size_t)j * 16 * 1024 + (kk + 1) * 32);
      }
      v8bf a[2];
      #pragma unroll
      for (int i = 0; i < 2; i++)
        a[i] = *(const v8bf*)(fs + kk * 1024 + (ln15 + 16 * i) * 32 + lq * 8);
      #pragma unroll
      for (int i = 0; i < 2; i++)
        #pragma unroll
        for (int j = 0; j < 4; j++)
          acc2[i][j] = __builtin_amdgcn_mfma_f32_16x16x32_bf16(a[i], ccur[j], acc2[i][j], 0, 0, 0);
      #pragma unroll
      for (int j = 0; j < 4; j++) ccur[j] = cnxt[j];
    }
    if (half == 0) __syncthreads();   // protect fs before next half rewrite
  }

  // ---- epilogue: x += acc2 + b2 (each (row,col) touched by exactly 1 lane)
  #pragma unroll
  for (int j = 0; j < 4; j++) {
    int colg = cb + 16 * j + ln15;
    float bb = b2p[colg];
    #pragma unroll
    for (int i = 0; i < 2; i++)
      #pragma unroll
      for (int r = 0; r < 4; r++) {
        int rowg = r0 + 16 * i + lq * 4 + r;
        size_t idx = (size_t)rowg * 256 + colg;
        xp[idx] += acc2[i][j][r] + bb;
      }
  }
}

// ---------------------------------------------------------------------------
// Attention: seq_len 3, H=8, DH=32. Input = fused qkv buffer, row stride 768
// ([q|k|v] per row); output o, row stride 256. 8 sequences per block.
// ---------------------------------------------------------------------------
__global__ __launch_bounds__(256)
void attn(const bf16* __restrict__ qkvp, bf16* __restrict__ op)
{
  __shared__ __align__(16) u16 qs[6144], ks[6144], vs[6144];
  __shared__ float probs[8][8][9];
  const int tid = threadIdx.x;
  const uint4* g = (const uint4*)qkvp + (size_t)blockIdx.x * 24 * 96;
  for (int c = tid; c < 768; c += 256) {
    int r = c >> 5, e = c & 31;
    ((uint4*)qs)[c] = g[r * 96 + e];
    ((uint4*)ks)[c] = g[r * 96 + 32 + e];
    ((uint4*)vs)[c] = g[r * 96 + 64 + e];
  }
  __syncthreads();
  if (tid < 64) {
    int s = tid >> 3, h = tid & 7;
    int base = s * 768 + h * 32;
    float sc[3][3];
    #pragma unroll
    for (int i = 0; i < 3; i++)
      #pragma unroll
      for (int j = 0; j < 3; j++) {
        float sum = 0.f;
        #pragma unroll
        for (int d = 0; d < 32; d++)
          sum += b2f(qs[base + i * 256 + d]) * b2f(ks[base + j * 256 + d]);
        sc[i][j] = sum * 0.17677669529663687f;
      }
    #pragma unroll
    for (int i = 0; i < 3; i++) {
      float m = fmaxf(sc[i][0], fmaxf(sc[i][1], sc[i][2]));
      float e0 = __expf(sc[i][0] - m);
      float e1 = __expf(sc[i][1] - m);
      float e2 = __expf(sc[i][2] - m);
      float inv = 1.f / (e0 + e1 + e2);
      probs[s][h][i * 3 + 0] = e0 * inv;
      probs[s][h][i * 3 + 1] = e1 * inv;
      probs[s][h][i * 3 + 2] = e2 * inv;
    }
  }
  __syncthreads();
  u16* og = (u16*)op + (size_t)blockIdx.x * 6144;
  for (int c = tid; c < 6144; c += 256) {
    int lrow = c >> 8, hd = c & 255;
    int s = lrow / 3, i = lrow - s * 3;
    int h = hd >> 5;
    float p0 = probs[s][h][i * 3 + 0];
    float p1 = probs[s][h][i * 3 + 1];
    float p2 = probs[s][h][i * 3 + 2];
    float o = p0 * b2f(vs[s * 768 + hd])
            + p1 * b2f(vs[s * 768 + 256 + hd])
            + p2 * b2f(vs[s * 768 + 512 + hd]);
    og[c] = f2b(o);
  }
}

// ---------------------------------------------------------------------------
// Final LN + mean over 3 tokens (f32 in, f32 out). 1 wave/seq, 4 seq/block.
// ---------------------------------------------------------------------------
__global__ __launch_bounds__(256)
void ln_final_mean(const float* __restrict__ xp, const float* __restrict__ gp,
                   const float* __restrict__ bp, float* __restrict__ outp)
{
  const int lane = threadIdx.x & 63;
  const int n = blockIdx.x * 4 + (threadIdx.x >> 6);
  float4 gv = *(const float4*)(gp + lane * 4);
  float4 bv4 = *(const float4*)(bp + lane * 4);
  float a0 = 0.f, a1 = 0.f, a2 = 0.f, a3 = 0.f;
  for (int t = 0; t < 3; t++) {
    float4 rv = *(const float4*)(xp + ((size_t)n * 3 + t) * 256 + lane * 4);
    float v0 = rv.x, v1 = rv.y, v2 = rv.z, v3 = rv.w;
    float s = v0 + v1 + v2 + v3;
    float q = v0 * v0 + v1 * v1 + v2 * v2 + v3 * v3;
    #pragma unroll
    for (int m = 32; m > 0; m >>= 1) {
      s += __shfl_xor(s, m, 64);
      q += __shfl_xor(q, m, 64);
    }
    float mean = s * (1.f / 256.f);
    float var = q * (1.f / 256.f) - mean * mean;
    float r = rsqrtf(var + 1e-5f);
    a0 += (v0 - mean) * r * gv.x + bv4.x;
    a1 += (v1 - mean) * r * gv.y + bv4.y;
    a2 += (v2 - mean) * r * gv.z + bv4.z;
    a3 += (v3 - mean) * r * gv.w + bv4.w;
  }
  const float third = 1.f / 3.f;
  float4 outv;
  outv.x = a0 * third;
  outv.y = a1 * third;
  outv.z = a2 * third;
  outv.w = a3 * third;
  *(float4*)(outp + (size_t)n * 256 + lane * 4) = outv;
}

// ---------------------------------------------------------------------------
extern "C" void kernel_launch(void* const* d_in, const int* in_sizes, int n_in,
                              void* d_out, int out_size, void* d_ws, size_t ws_size,
                              hipStream_t stream)
{
  const float* term = (const float*)d_in[0];
  const float* pred = (const float*)d_in[1];
  const float* Wq  = (const float*)d_in[2];
  const float* Wk  = (const float*)d_in[3];
  const float* Wv  = (const float*)d_in[4];
  const float* Wo  = (const float*)d_in[5];
  const float* bq  = (const float*)d_in[6];
  const float* bk  = (const float*)d_in[7];
  const float* bvv = (const float*)d_in[8];
  const float* bo  = (const float*)d_in[9];
  const float* ln1g = (const float*)d_in[10];
  const float* ln1b = (const float*)d_in[11];
  const float* ln2g = (const float*)d_in[12];
  const float* ln2b = (const float*)d_in[13];
  const float* W1  = (const float*)d_in[14];
  const float* b1  = (const float*)d_in[15];
  const float* W2  = (const float*)d_in[16];
  const float* b2  = (const float*)d_in[17];
  const float* lnfg = (const float*)d_in[18];
  const float* lnfb = (const float*)d_in[19];

  // Per chunk per row: x f32 (1024B) + h bf16 (512B) + qkv bf16 (1536B) +
  // o bf16 (512B) = 3584B. (FFN hidden lives in LDS.)
  int nch = 128;
  for (int c = 1; c <= 128; c *= 2) {
    size_t Mc = (size_t)MROWS / c;
    size_t need = 4ull * 1024 * 1024 + Mc * 3584ull;
    if (need <= ws_size) { nch = c; break; }
  }
  const size_t Mc = (size_t)MROWS / nch;     // multiple of 1152
  const int mBlocks = (int)(Mc / 128);

  char* ws = (char*)d_ws;
  bf16* wt   = (bf16*)ws;                    // 1572864 el (3 MB)
  float* bqkv = (float*)(ws + 3145728);      // 1536 f32
  float* x = (float*)(ws + 4194304);         // Mc*256 f32
  bf16* h = (bf16*)(x + Mc * 256);           // Mc*256 bf16
  bf16* qkv = h + Mc * 256;                  // Mc*768 bf16
  bf16* o = qkv + Mc * 768;                  // Mc*256 bf16

  prep_weights<<<6145, 256, 0, stream>>>(Wq, Wk, Wv, Wo, W1, W2, bq, bk, bvv, wt, bqkv);

  for (int ch = 0; ch < nch; ch++) {
    const int row0 = (int)(ch * Mc);
    build_ln<<<(int)(Mc / 4), 256, 0, stream>>>(term, pred, ln1g, ln1b, x, h, row0);
    for (int l = 0; l < 2; l++) {
      const bf16* wl = wt + l * 786432;
      if (l > 0)
        ln_rows<<<(int)(Mc / 4), 256, 0, stream>>>(x, ln1g + l * 256, ln1b + l * 256, h);
      gemm_bt<0, 0><<<dim3(mBlocks, 6), 256, 0, stream>>>(
          h, wl, bqkv + l * 768, nullptr, qkv, 768, 256);
      attn<<<(int)(Mc / 24), 256, 0, stream>>>(qkv, o);
      gemm_bt<1, 1><<<dim3(mBlocks, 2), 256, 0, stream>>>(
          o, wl + 196608, bo + l * 256, x, x, 256, 256);
      ffn_fused<<<(int)(Mc / 32), 256, 0, stream>>>(
          x, (const bf16*)(wl + 262144), (const bf16*)(wl + 524288),
          ln2g + l * 256, ln2b + l * 256, b1 + l * 1024, b2 + l * 256);
    }
    ln_final_mean<<<(int)(Mc / 12), 256, 0, stream>>>(
        x, lnfg, lnfb, (float*)d_out + (size_t)(row0 / 3) * 256);
  }
}